// Round 9
// baseline (239.676 us; speedup 1.0000x reference)
//
#include <hip/hip_runtime.h>
#include <hip/hip_bf16.h>
#include <stdint.h>

#define Bn 8
#define Sn 4096
#define Hn 768
#define Dn 1024
#define Wn 2048

typedef __attribute__((ext_vector_type(8))) short short8;
typedef __attribute__((ext_vector_type(4))) short short4v;
typedef __attribute__((ext_vector_type(4))) float floatx4;

__device__ __forceinline__ void load_lds16(const void* g, void* l) {
  __builtin_amdgcn_global_load_lds(
      (const __attribute__((address_space(1))) void*)g,
      (__attribute__((address_space(3))) void*)l, 16, 0, 0);
}

// lane-parallel lower_bound over a sorted 4096-int array (wave-uniform result).
__device__ __forceinline__ int lb4096(const int* __restrict__ a, int x, int lane) {
  const int p = a[lane << 6];
  const unsigned long long m1 = __ballot(p < x);
  const int n1 = __popcll(m1);
  const int base = (n1 > 0 ? n1 - 1 : 0) << 6;
  const int q = a[base + lane];
  const unsigned long long m2 = __ballot(q < x);
  return base + __popcll(m2);
}

// -------- kernel 1: proj_w transpose  ∥  segment means + masks ------------------
// (bit-identical to round 6 — measured best 204.4 µs)
__global__ __launch_bounds__(256) void k_front(const float* __restrict__ emb,
                                               const float* __restrict__ pw,
                                               const int* __restrict__ masks,
                                               const int* __restrict__ wid,
                                               __hip_bfloat16* __restrict__ wb,
                                               __hip_bfloat16* __restrict__ wa,
                                               float* __restrict__ out_masks) {
  const int bid = blockIdx.x;
  if (bid < 768) {
    __shared__ float tile[32][33];
    const int bt = bid;                   // 32 x 24 tile grid
    const int d0 = (bt % 32) * 32, h0 = (bt / 32) * 32;
    const int tx = threadIdx.x & 31, ty = threadIdx.x >> 5;  // 32 x 8
#pragma unroll
    for (int i = 0; i < 32; i += 8)
      tile[ty + i][tx] = pw[(size_t)(h0 + ty + i) * Dn + d0 + tx];
    __syncthreads();
#pragma unroll
    for (int i = 0; i < 32; i += 8)
      wb[(size_t)(d0 + ty + i) * Hn + h0 + tx] = (__hip_bfloat16)tile[tx][ty + i];
    return;
  }

  const int wbid = bid - 768;                // 0 .. 4095
  const int b = wbid >> 9;                   // 512 blocks per batch
  const int wave = threadIdx.x >> 6, lane = threadIdx.x & 63;
  const int w = (wbid & 511) * 4 + wave;

  const int* wbi = wid + (size_t)b * Sn;
  const int start = lb4096(wbi, w, lane);
  const int end = lb4096(wbi, w + 1, lane);
  const int count = end - start;

  const int* mb = masks + (size_t)b * Sn;
  bool allone = true;
  for (int s0 = start; s0 < end; s0 += 64) {
    const int idx = s0 + lane;
    allone = allone && ((idx < end) ? (mb[idx] == 1) : true);
  }
  const bool valid = (count > 0) && __all(allone);
  const float inv = valid ? 1.0f / (float)count : 0.0f;

  floatx4 sum[3] = {{0.f, 0.f, 0.f, 0.f}, {0.f, 0.f, 0.f, 0.f}, {0.f, 0.f, 0.f, 0.f}};
  const float* eb = emb + (size_t)b * Sn * Hn;
  int s = start;
  for (; s + 1 < end; s += 2) {
    const floatx4* r0 = (const floatx4*)(eb + (size_t)s * Hn);
    const floatx4* r1 = (const floatx4*)(eb + (size_t)(s + 1) * Hn);
#pragma unroll
    for (int j = 0; j < 3; ++j) sum[j] += r0[j * 64 + lane];
#pragma unroll
    for (int j = 0; j < 3; ++j) sum[j] += r1[j * 64 + lane];
  }
  if (s < end) {
    const floatx4* r0 = (const floatx4*)(eb + (size_t)s * Hn);
#pragma unroll
    for (int j = 0; j < 3; ++j) sum[j] += r0[j * 64 + lane];
  }

  const size_t rowbase = ((size_t)b * Wn + w) * Hn;
#pragma unroll
  for (int j = 0; j < 3; ++j) {
    short4v o;
#pragma unroll
    for (int c = 0; c < 4; ++c) {
      __hip_bfloat16 h = (__hip_bfloat16)(sum[j][c] * inv);
      o[c] = *reinterpret_cast<short*>(&h);
    }
    *(short4v*)&wa[rowbase + (size_t)(j * 64 + lane) * 4] = o;
  }
  if (lane == 0) out_masks[(size_t)b * Wn + w] = valid ? 1.0f : 0.0f;
}

// ------------- kernel 2: bf16 MFMA GEMM  C = A @ B^T + bias ---------------------
// (bit-identical to round 6 — 256x256 tile, BK=64, dbuf, stage-early,
//  peeled store-fused last K-tile)
constexpr int GK = Hn;            // 768
constexpr int TS = 256 * 64;      // shorts per A (or B) region = 32 KiB
constexpr int kGemmLds = 2 * 2 * TS * (int)sizeof(short);  // 131072 B
static_assert(kGemmLds == 131072, "LDS budget");

__global__ __launch_bounds__(512, 2) void k_gemm(const short* __restrict__ A,
                                                 const short* __restrict__ Bt,
                                                 const float* __restrict__ bias,
                                                 float* __restrict__ out) {
  extern __shared__ __align__(16) short ls[];  // [2][A 16384 | B 16384]

  const int t = threadIdx.x;  // 0..511
  const int lane = t & 63, wave = t >> 6;
  const int wm = wave >> 2, wn = wave & 3;        // 2 x 4 wave grid
  const int lane16 = lane & 15, quad = lane >> 4;
  const int swz = lane16 & 7;

  const int mt = blockIdx.x & 63, nt = blockIdx.x >> 6;
  const int m0 = mt * 256, n0 = nt * 256;

  const int rS = t >> 3;
  const int csw = ((t & 7) ^ (rS & 7)) * 8;  // shorts
  const short* gAs = A + (size_t)(m0 + rS) * GK + csw;
  const short* gBs = Bt + (size_t)(n0 + rS) * GK + csw;
  const int dst0 = t * 8;  // = rS*64 + (t&7)*8

  auto stage_a = [&](int buf, int kt) {
    short* d = ls + buf * 2 * TS + dst0;
    const short* g = gAs + kt * 64;
#pragma unroll
    for (int j = 0; j < 4; ++j) load_lds16(g + (size_t)(j * 64) * GK, d + j * 4096);
  };
  auto stage_b = [&](int buf, int kt) {
    short* d = ls + buf * 2 * TS + TS + dst0;
    const short* g = gBs + kt * 64;
#pragma unroll
    for (int j = 0; j < 4; ++j) load_lds16(g + (size_t)(j * 64) * GK, d + j * 4096);
  };

  auto ld_a = [&](short8(&af)[4][2], int qm, const short* bufA) {
#pragma unroll
    for (int mf = 0; mf < 4; ++mf)
#pragma unroll
      for (int ks = 0; ks < 2; ++ks)
        af[mf][ks] = *(const short8*)&bufA[(wm * 128 + qm * 64 + mf * 16 + lane16) * 64 +
                                           ((((ks << 2) | quad) ^ swz) << 3)];
  };
  auto ld_b = [&](short8(&bf)[2][2], int qn, const short* bufB) {
#pragma unroll
    for (int nf = 0; nf < 2; ++nf)
#pragma unroll
      for (int ks = 0; ks < 2; ++ks)
        bf[nf][ks] = *(const short8*)&bufB[(wn * 64 + qn * 32 + nf * 16 + lane16) * 64 +
                                           ((((ks << 2) | quad) ^ swz) << 3)];
  };

  floatx4 acc[8][4];
#pragma unroll
  for (int i = 0; i < 8; ++i)
#pragma unroll
    for (int j = 0; j < 4; ++j) acc[i][j] = (floatx4){0.f, 0.f, 0.f, 0.f};

  auto mm = [&](short8(&af)[4][2], short8(&bf)[2][2], int qm, int qn) {
    __builtin_amdgcn_s_setprio(1);
#pragma unroll
    for (int mf = 0; mf < 4; ++mf)
#pragma unroll
      for (int nf = 0; nf < 2; ++nf)
#pragma unroll
        for (int ks = 0; ks < 2; ++ks)
          acc[qm * 4 + mf][qn * 2 + nf] = __builtin_amdgcn_mfma_f32_16x16x32_bf16(
              af[mf][ks], bf[nf][ks], acc[qm * 4 + mf][qn * 2 + nf], 0, 0, 0);
    __builtin_amdgcn_s_setprio(0);
  };

  float bv[4];
#pragma unroll
  for (int nf = 0; nf < 4; ++nf) bv[nf] = bias[n0 + wn * 64 + nf * 16 + lane16];

  auto store_quad = [&](int qm, int qn) {
#pragma unroll
    for (int mf = 0; mf < 4; ++mf) {
#pragma unroll
      for (int nf = 0; nf < 2; ++nf) {
        const int n = n0 + wn * 64 + (qn * 2 + nf) * 16 + lane16;
#pragma unroll
        for (int r = 0; r < 4; ++r) {
          const int m = m0 + wm * 128 + (qm * 4 + mf) * 16 + quad * 4 + r;
          __builtin_nontemporal_store(acc[qm * 4 + mf][qn * 2 + nf][r] + bv[qn * 2 + nf],
                                      &out[(size_t)m * Dn + n]);
        }
      }
    }
  };

  stage_a(0, 0);
  stage_b(0, 0);
  __syncthreads();

#pragma unroll 1
  for (int kt = 0; kt < 11; ++kt) {
    const short* bufA = ls + (kt & 1) * 2 * TS;
    const short* bufB = bufA + TS;
    const int nb = (kt + 1) & 1;
    short8 af[4][2], b0[2][2], b1[2][2];

    ld_a(af, 0, bufA);
    ld_b(b0, 0, bufB);
    stage_a(nb, kt + 1);
    mm(af, b0, 0, 0);

    ld_b(b1, 1, bufB);
    stage_b(nb, kt + 1);
    mm(af, b1, 0, 1);

    ld_a(af, 1, bufA);
    mm(af, b1, 1, 1);

    mm(af, b0, 1, 0);

    __syncthreads();
  }

  {
    const short* bufA = ls + (11 & 1) * 2 * TS;
    const short* bufB = bufA + TS;
    short8 af[4][2], b0[2][2], b1[2][2];

    ld_a(af, 0, bufA);
    ld_b(b0, 0, bufB);
    mm(af, b0, 0, 0);
    store_quad(0, 0);

    ld_b(b1, 1, bufB);
    mm(af, b1, 0, 1);
    store_quad(0, 1);

    ld_a(af, 1, bufA);
    mm(af, b1, 1, 1);
    store_quad(1, 1);

    mm(af, b0, 1, 0);
    store_quad(1, 0);
  }
}

extern "C" void kernel_launch(void* const* d_in, const int* in_sizes, int n_in,
                              void* d_out, int out_size, void* d_ws, size_t ws_size,
                              hipStream_t stream) {
  const float* emb    = (const float*)d_in[0];  // (8, 4096, 768)
  const float* proj_w = (const float*)d_in[1];  // (768, 1024)
  const float* proj_b = (const float*)d_in[2];  // (1024,)
  const int*   masks  = (const int*)d_in[3];    // (8, 4096)
  const int*   wid    = (const int*)d_in[4];    // (8, 4096)

  float* out = (float*)d_out;                       // (8, 2048, 1024) fp32
  float* out_masks = out + (size_t)Bn * Wn * Dn;    // (8, 2048) as 0.0/1.0

  __hip_bfloat16* wb = (__hip_bfloat16*)d_ws;            // B^T: (1024, 768) bf16
  __hip_bfloat16* wa = wb + (size_t)Dn * Hn;             // A:   (16384, 768) bf16

  // 1. transpose (first 768 blocks) ∥ segment means + masks (4096 blocks)
  k_front<<<dim3(768 + 4096), 256, 0, stream>>>(emb, proj_w, masks, wid, wb, wa,
                                                out_masks);

  (void)hipFuncSetAttribute((const void*)k_gemm,
                            hipFuncAttributeMaxDynamicSharedMemorySize, kGemmLds);

  // 2. projection GEMM + bias.
  k_gemm<<<dim3(256), 512, kGemmLds, stream>>>((const short*)wa, (const short*)wb,
                                               proj_b, out);

  // 3. DIAGNOSTIC (this round only): identical second GEMM launch. Idempotent
  //    (same inputs, rewrites identical values to out). dur_us delta vs round 6
  //    = t_gemm + launch gap — the first direct measurement of the GEMM's
  //    in-graph cost, since rocprof top-5 only surfaces >58 µs dispatches.
  k_gemm<<<dim3(256), 512, kGemmLds, stream>>>((const short*)wa, (const short*)wb,
                                               proj_b, out);
}